// Round 6
// baseline (838.677 us; speedup 1.0000x reference)
//
#include <hip/hip_runtime.h>
#include <hip/hip_fp16.h>

namespace {
constexpr int Bn = 64;
constexpr int Tn = 1024;
constexpr int Kn = 256;

typedef _Float16 half8 __attribute__((ext_vector_type(8)));
typedef float f32x4 __attribute__((ext_vector_type(4)));

// ---- DPP wave-64 reductions ----
template <int C>
__device__ __forceinline__ float dppmax1(float x) {
    int o = __builtin_bit_cast(int, x);
    int y = __builtin_amdgcn_update_dpp(o, o, C, 0xF, 0xF, false);
    return fmaxf(x, __builtin_bit_cast(float, y));
}
template <int C>
__device__ __forceinline__ float dppadd1(float x) {
    int y = __builtin_amdgcn_update_dpp(0, __builtin_bit_cast(int, x), C, 0xF, 0xF, true);
    return x + __builtin_bit_cast(float, y);
}
__device__ __forceinline__ float wave_max64(float x) {
    x = dppmax1<0x111>(x);
    x = dppmax1<0x112>(x);
    x = dppmax1<0x114>(x);
    x = dppmax1<0x118>(x);
    x = dppmax1<0x142>(x);  // row_bcast:15
    x = dppmax1<0x143>(x);  // row_bcast:31
    return __builtin_bit_cast(float,
        __builtin_amdgcn_readlane(__builtin_bit_cast(int, x), 63));
}
__device__ __forceinline__ float wave_sum64(float x) {
    x = dppadd1<0x111>(x);
    x = dppadd1<0x112>(x);
    x = dppadd1<0x114>(x);
    x = dppadd1<0x118>(x);
    x = dppadd1<0x142>(x);
    x = dppadd1<0x143>(x);
    return __builtin_bit_cast(float,
        __builtin_amdgcn_readlane(__builtin_bit_cast(int, x), 63));
}

// Workgroup barrier that drains ONLY LDS (lgkmcnt), leaving global loads
// (vmcnt) in flight across the barrier. __syncthreads() would emit
// s_waitcnt vmcnt(0) and stall ~900 cyc on the emission prefetch stream.
__device__ __forceinline__ void wg_barrier_lds_only() {
    __asm__ volatile("s_waitcnt lgkmcnt(0)" ::: "memory");
    __builtin_amdgcn_s_barrier();
    __asm__ volatile("" ::: "memory");
}

__global__ __launch_bounds__(256, 1) void crf_kernel(
    const float* __restrict__ inputs,     // (B,T,K)
    const long long* __restrict__ tags,   // (B,T)
    const int* __restrict__ mask,         // (B,T)
    const float* __restrict__ trans,      // (K,K)
    const float* __restrict__ start_t,    // (K,)
    const float* __restrict__ end_t,      // (K,)
    float* __restrict__ out)              // scalar
{
    const int b   = blockIdx.x;
    const int tid = threadIdx.x;
    const int w   = tid >> 6;       // wave 0..3, owns j in [64w, 64w+64)
    const int l   = tid & 63;
    const int La  = l >> 4;         // 0..3
    const int lc  = l & 15;

    const int j_own = 64 * w + 16 * La + lc;   // unique tag per lane

    __shared__ __align__(16) _Float16 p_sh[2][Kn];  // double-buffered p row (f16)
    __shared__ __align__(16) float Mvf[2][4];       // per-wave alpha max
    __shared__ float red[4][2];
    __shared__ float sh_np;
    __shared__ int   sh_len;

    // ---- E as MFMA B-fragments:
    // Bfrag[c][kt] holds B[k = 32kt + 8La + i][n = 64w + 16c + lc] = exp(trans[k][n])
    half8 Bfrag[4][8];
#pragma unroll
    for (int c = 0; c < 4; ++c) {
        const int n = 64 * w + 16 * c + lc;
#pragma unroll
        for (int kt = 0; kt < 8; ++kt) {
            half8 hb;
#pragma unroll
            for (int i = 0; i < 8; ++i) {
                const int k = 32 * kt + 8 * La + i;
                hb[i] = (_Float16)__expf(trans[k * Kn + n]);
            }
            Bfrag[c][kt] = hb;
        }
    }

    if (tid == 0) { sh_len = 0; sh_np = 0.f; }
    __syncthreads();

    // ---- sequence length
    {
        int c = 0;
        for (int t = tid; t < Tn; t += 256) c += (mask[b * Tn + t] > 0) ? 1 : 0;
        float cf = wave_sum64((float)c);
        if (l == 0) atomicAdd(&sh_len, (int)(cf + 0.5f));
    }
    __syncthreads();
    const int end_idx = sh_len - 1;

    const float endj = end_t[j_own];
    const size_t bTK = (size_t)b * Tn * Kn;

    // ---- alpha init (t = 0), one j per lane
    float alpha = inputs[bTK + j_own] + start_t[j_own] +
                  (end_idx == 0 ? endj : 0.f);

    // ---- 3-deep prefetch of emissions + mask
    float lg1 = inputs[bTK + 1 * (size_t)Kn + j_own];
    int   mk1 = mask[b * Tn + 1];
    float lg2 = inputs[bTK + 2 * (size_t)Kn + j_own];
    int   mk2 = mask[b * Tn + 2];
    float lg3 = inputs[bTK + 3 * (size_t)Kn + j_own];
    int   mk3 = mask[b * Tn + 3];

    // ---- pre-loop: block max of alpha(0) -> scale for p(0)
    {
        const float wmx = wave_max64(alpha);
        if (l == 0) Mvf[0][w] = wmx;
    }
    __syncthreads();
    float R_prev;
    {
        const float4 mv = *(const float4*)(&Mvf[0][0]);
        R_prev = fmaxf(fmaxf(mv.x, mv.y), fmaxf(mv.z, mv.w));
        const float pv = __expf(fminf(alpha - R_prev, 11.0f));
        p_sh[0][j_own] = (_Float16)pv;
    }

    // ---- forward recursion: one LDS-only barrier per step
    for (int t = 1; t < Tn; ++t) {
        wg_barrier_lds_only();

        const int pb = (t - 1) & 1;
        const int nb = t & 1;

        // rotate prefetch pipeline; issue next load immediately (stays in
        // flight across the next barrier — vmcnt NOT drained there)
        const float lgC = lg1;
        const int   mkC = mk1;
        lg1 = lg2; mk1 = mk2;
        lg2 = lg3; mk2 = mk3;
        const int tp = (t + 3 < Tn) ? (t + 3) : (Tn - 1);
        lg3 = inputs[bTK + (size_t)tp * Kn + j_own];
        mk3 = mask[b * Tn + tp];

        // R_next = max_j alpha(t-1): one broadcast b128 read
        const float4 mv = *(const float4*)(&Mvf[pb][0]);
        const float R_next = fmaxf(fmaxf(mv.x, mv.y), fmaxf(mv.z, mv.w));

        // A-fragments of replicated p: 8 broadcast b128 reads
        const half8* prow = (const half8*)(&p_sh[pb][0]);
        half8 af[8];
#pragma unroll
        for (int kt = 0; kt < 8; ++kt) af[kt] = prow[kt * 4 + La];

        // 4 N-tiles × 2 half-K chains (depth 4 each) -> shorter dep chains
        f32x4 a0l = {0,0,0,0}, a0h = {0,0,0,0};
        f32x4 a1l = {0,0,0,0}, a1h = {0,0,0,0};
        f32x4 a2l = {0,0,0,0}, a2h = {0,0,0,0};
        f32x4 a3l = {0,0,0,0}, a3h = {0,0,0,0};
#pragma unroll
        for (int kt = 0; kt < 4; ++kt) {
            a0l = __builtin_amdgcn_mfma_f32_16x16x32_f16(af[kt], Bfrag[0][kt], a0l, 0, 0, 0);
            a1l = __builtin_amdgcn_mfma_f32_16x16x32_f16(af[kt], Bfrag[1][kt], a1l, 0, 0, 0);
            a2l = __builtin_amdgcn_mfma_f32_16x16x32_f16(af[kt], Bfrag[2][kt], a2l, 0, 0, 0);
            a3l = __builtin_amdgcn_mfma_f32_16x16x32_f16(af[kt], Bfrag[3][kt], a3l, 0, 0, 0);
            a0h = __builtin_amdgcn_mfma_f32_16x16x32_f16(af[kt + 4], Bfrag[0][kt + 4], a0h, 0, 0, 0);
            a1h = __builtin_amdgcn_mfma_f32_16x16x32_f16(af[kt + 4], Bfrag[1][kt + 4], a1h, 0, 0, 0);
            a2h = __builtin_amdgcn_mfma_f32_16x16x32_f16(af[kt + 4], Bfrag[2][kt + 4], a2h, 0, 0, 0);
            a3h = __builtin_amdgcn_mfma_f32_16x16x32_f16(af[kt + 4], Bfrag[3][kt + 4], a3h, 0, 0, 0);
        }
        // D rows replicated; lane's own tile is c = La, col lc at element [0]
        const float s = (La == 0) ? (a0l[0] + a0h[0])
                      : (La == 1) ? (a1l[0] + a1h[0])
                      : (La == 2) ? (a2l[0] + a2h[0])
                                  : (a3l[0] + a3h[0]);

        const float na = R_prev + __logf(s) + lgC + (t == end_idx ? endj : 0.f);
        if (mkC > 0) alpha = na;

        // publish p(t) with delayed scale; record wave max for next step
        const float pv = __expf(fminf(alpha - R_next, 11.0f));
        p_sh[nb][j_own] = (_Float16)pv;
        const float wmx = wave_max64(alpha);
        if (l == 0) Mvf[nb][w] = wmx;

        R_prev = R_next;
    }

    // ---- denominator = logsumexp over all 256 alphas (one per lane)
    {
        const float wm = wave_max64(alpha);
        const float ex = __expf(alpha - wm);
        const float sw = wave_sum64(ex);
        if (l == 0) { red[w][0] = wm; red[w][1] = sw; }
    }

    // ---- numerator (gather path score)
    float np = 0.f;
    for (int t = tid; t < Tn; t += 256) {
        const int   tg = (int)tags[b * Tn + t];
        const float e  = inputs[bTK + (size_t)t * Kn + tg];
        if (t == 0) {
            np += e + start_t[tg];
        } else {
            const float mf = (float)mask[b * Tn + t];
            const int   tq = (int)tags[b * Tn + t - 1];
            np += mf * (e + trans[tq * Kn + tg]);
        }
    }
    np = wave_sum64(np);
    if (l == 0) atomicAdd(&sh_np, np);
    __syncthreads();

    if (tid == 0) {
        float Rf = red[0][0];
#pragma unroll
        for (int q = 1; q < 4; ++q) Rf = fmaxf(Rf, red[q][0]);
        float S = 0.f;
#pragma unroll
        for (int q = 0; q < 4; ++q) S += red[q][1] * __expf(red[q][0] - Rf);
        const float denom = Rf + __logf(S);
        const float numer = sh_np + end_t[(int)tags[b * Tn + end_idx]];
        atomicAdd(out, numer - denom);
    }
}

}  // namespace

extern "C" void kernel_launch(void* const* d_in, const int* in_sizes, int n_in,
                              void* d_out, int out_size, void* d_ws, size_t ws_size,
                              hipStream_t stream) {
    const float*     inputs  = (const float*)d_in[0];
    const long long* tags    = (const long long*)d_in[1];
    const int*       mask    = (const int*)d_in[2];
    const float*     trans   = (const float*)d_in[3];
    const float*     start_t = (const float*)d_in[4];
    const float*     end_t   = (const float*)d_in[5];
    float* out = (float*)d_out;

    hipMemsetAsync(out, 0, sizeof(float), stream);
    crf_kernel<<<dim3(Bn), dim3(256), 0, stream>>>(inputs, tags, mask, trans,
                                                   start_t, end_t, out);
}

// Round 9
// 728.184 us; speedup vs baseline: 1.1517x; 1.1517x over previous
//
#include <hip/hip_runtime.h>
#include <hip/hip_fp16.h>

namespace {
constexpr int Bn = 64;
constexpr int Tn = 1024;
constexpr int Kn = 256;
constexpr float LOG2E = 1.4426950408889634f;
constexpr float LN2   = 0.6931471805599453f;

typedef int   int8v __attribute__((ext_vector_type(8)));
typedef float f32x4 __attribute__((ext_vector_type(4)));

__device__ __forceinline__ int imax(int a, int b) { return a > b ? a : b; }

// exact decode of OCP e4m3fn byte
__device__ __forceinline__ float dec_e4m3(int v) {
    const int e = (v >> 3) & 0xF;
    const int m = v & 7;
    float mag = e ? ldexpf(1.0f + 0.125f * (float)m, e - 7)
                  : ldexpf(0.125f * (float)m, -6);
    return (v & 0x80) ? -mag : mag;
}

// ---- DPP wave-64 reductions ----
template <int C>
__device__ __forceinline__ float dppmax1(float x) {
    int o = __builtin_bit_cast(int, x);
    int y = __builtin_amdgcn_update_dpp(o, o, C, 0xF, 0xF, false);
    return fmaxf(x, __builtin_bit_cast(float, y));
}
template <int C>
__device__ __forceinline__ float dppadd1(float x) {
    int y = __builtin_amdgcn_update_dpp(0, __builtin_bit_cast(int, x), C, 0xF, 0xF, true);
    return x + __builtin_bit_cast(float, y);
}
__device__ __forceinline__ float wave_max64(float x) {
    x = dppmax1<0x111>(x);
    x = dppmax1<0x112>(x);
    x = dppmax1<0x114>(x);
    x = dppmax1<0x118>(x);
    x = dppmax1<0x142>(x);  // row_bcast:15
    x = dppmax1<0x143>(x);  // row_bcast:31
    return __builtin_bit_cast(float,
        __builtin_amdgcn_readlane(__builtin_bit_cast(int, x), 63));
}
__device__ __forceinline__ float wave_sum64(float x) {
    x = dppadd1<0x111>(x);
    x = dppadd1<0x112>(x);
    x = dppadd1<0x114>(x);
    x = dppadd1<0x118>(x);
    x = dppadd1<0x142>(x);
    x = dppadd1<0x143>(x);
    return __builtin_bit_cast(float,
        __builtin_amdgcn_readlane(__builtin_bit_cast(int, x), 63));
}

// Barrier draining only LDS (lgkmcnt); emission prefetch stays in flight.
__device__ __forceinline__ void wg_barrier_lds_only() {
    __asm__ volatile("s_waitcnt lgkmcnt(0)" ::: "memory");
    __builtin_amdgcn_s_barrier();
    __asm__ volatile("" ::: "memory");
}

// software round-to-nearest encode of v (>0, < 2^15.9) into OCP e5m2 byte
__device__ __forceinline__ int enc_e5m2(float v) {
    int bits = __builtin_bit_cast(int, v);
    bits += (1 << 20);                    // round at 2-bit mantissa
    const int ee = (bits >> 23) - 112;    // e5m2 exponent field
    int byte = (ee << 2) | ((bits >> 21) & 3);
    byte = (ee > 30) ? 0x7B : byte;       // saturate to 57344
    const int dnm = (int)(v * 65536.0f + 0.5f);  // denormals: m * 2^-16
    return (ee >= 1) ? byte : dnm;
}

__global__ __launch_bounds__(512, 2) void crf_kernel(
    const float* __restrict__ inputs,     // (B,T,K)
    const long long* __restrict__ tags,   // (B,T)
    const int* __restrict__ mask,         // (B,T)
    const float* __restrict__ trans,      // (K,K)
    const float* __restrict__ start_t,    // (K,)
    const float* __restrict__ end_t,      // (K,)
    float* __restrict__ out)              // scalar
{
    const int b   = blockIdx.x;
    const int tid = threadIdx.x;
    const int w   = tid >> 6;       // wave 0..7, owns j in [32w, 32w+32)
    const int l   = tid & 63;
    const int La  = l >> 4;         // k-chunk / column group 0..3
    const int lc  = l & 15;

    const int j_own = 32 * w + 16 * (La & 1) + lc;  // dup on lanes La and La+2

    __shared__ __align__(32) unsigned char p8[2][Kn];  // bf8 p row, dbuf
    __shared__ __align__(16) int msh[2][8];            // per-wave pow2 anchors
    __shared__ float red[8][2];
    __shared__ float sh_np;
    __shared__ int   sh_len;

    // ---- E as split hi/lo fp8 e4m3 B-fragments (E = Ehi + 2^-4*Elo, unbiased)
    int8v Bhi[2][2], Blo[2][2];
#pragma unroll
    for (int c = 0; c < 2; ++c) {
        const int n = 32 * w + 16 * c + lc;
#pragma unroll
        for (int h = 0; h < 2; ++h) {
#pragma unroll
            for (int r = 0; r < 8; ++r) {
                const int ib = 128 * h + 32 * La + 4 * r;
                float f0 = __expf(trans[(ib + 0) * Kn + n]);
                float f1 = __expf(trans[(ib + 1) * Kn + n]);
                float f2 = __expf(trans[(ib + 2) * Kn + n]);
                float f3 = __expf(trans[(ib + 3) * Kn + n]);
                int dhi = __builtin_amdgcn_cvt_pk_fp8_f32(f0, f1, 0, false);
                dhi = __builtin_amdgcn_cvt_pk_fp8_f32(f2, f3, dhi, true);
                const float r0 = (f0 - dec_e4m3((dhi >> 0) & 0xFF)) * 16.f;
                const float r1 = (f1 - dec_e4m3((dhi >> 8) & 0xFF)) * 16.f;
                const float r2 = (f2 - dec_e4m3((dhi >> 16) & 0xFF)) * 16.f;
                const float r3 = (f3 - dec_e4m3((dhi >> 24) & 0xFF)) * 16.f;
                int dlo = __builtin_amdgcn_cvt_pk_fp8_f32(r0, r1, 0, false);
                dlo = __builtin_amdgcn_cvt_pk_fp8_f32(r2, r3, dlo, true);
                Bhi[c][h][r] = dhi;
                Blo[c][h][r] = dlo;
            }
        }
    }

    if (tid == 0) { sh_len = 0; sh_np = 0.f; }
    __syncthreads();

    // ---- sequence length
    {
        int c = 0;
        for (int t = tid; t < Tn; t += 512) c += (mask[b * Tn + t] > 0) ? 1 : 0;
        float cf = wave_sum64((float)c);
        if (l == 0) atomicAdd(&sh_len, (int)(cf + 0.5f));
    }
    __syncthreads();
    const int end_idx = sh_len - 1;

    const float endj = end_t[j_own];
    const size_t bTK = (size_t)b * Tn * Kn;

    // ---- alpha init (t = 0)
    float alpha = inputs[bTK + j_own] + start_t[j_own] +
                  (end_idx == 0 ? endj : 0.f);

    // ---- 3-deep prefetch of emissions + mask
    float lg1 = inputs[bTK + 1 * (size_t)Kn + j_own];
    int   mk1 = mask[b * Tn + 1];
    float lg2 = inputs[bTK + 2 * (size_t)Kn + j_own];
    int   mk2 = mask[b * Tn + 2];
    float lg3 = inputs[bTK + 3 * (size_t)Kn + j_own];
    int   mk3 = mask[b * Tn + 3];

    // publish p(t) = 2^(alpha*log2e - rs) as bf8 e5m2 (GLOBAL integer anchor rs
    // -> all MFMA scale bytes uniform; also record this step's wave anchor)
    auto publish = [&](float av, int nb, int rs) {
        const float wmx = wave_max64(av);
        if (l == 0) msh[nb][w] = (int)ceilf(wmx * LOG2E);
        const float p = exp2f(av * LOG2E - (float)rs);
        const int byte = enc_e5m2(p);
        if (La < 2) p8[nb][j_own] = (unsigned char)byte;
    };

    // ---- pre-loop: anchors of alpha(0) -> global r0, publish p(0)
    {
        const float wmx = wave_max64(alpha);
        if (l == 0) msh[0][w] = (int)ceilf(wmx * LOG2E);
    }
    __syncthreads();
    int R_prev;
    {
        const int4 m0 = *(const int4*)(&msh[0][0]);
        const int4 m1 = *(const int4*)(&msh[0][4]);
        R_prev = imax(imax(imax(m0.x, m0.y), imax(m0.z, m0.w)),
                      imax(imax(m1.x, m1.y), imax(m1.z, m1.w)));
        publish(alpha, 0, R_prev);   // rewrites msh[0][w] with same value (benign)
    }

    // ---- forward recursion, one LDS-only barrier per step
    for (int t = 1; t < Tn; ++t) {
        wg_barrier_lds_only();

        const int pb = (t - 1) & 1;
        const int nb = t & 1;

        const float lgC = lg1;
        const int   mkC = mk1;
        lg1 = lg2; mk1 = mk2;
        lg2 = lg3; mk2 = mk3;
        const int tp = (t + 3) & (Tn - 1);   // wrap: tail loads never consumed
        lg3 = inputs[bTK + (size_t)tp * Kn + j_own];
        mk3 = mask[b * Tn + tp];

        // r = global anchor of alpha(t-1): scale for THIS step's publish
        const int4 m0 = *(const int4*)(&msh[pb][0]);
        const int4 m1 = *(const int4*)(&msh[pb][4]);
        const int r = imax(imax(imax(m0.x, m0.y), imax(m0.z, m0.w)),
                           imax(imax(m1.x, m1.y), imax(m1.z, m1.w)));

        // A-fragments: lane reads its 32-byte k-run (broadcast per La group)
        const int8v* ap = (const int8v*)(&p8[pb][0]);
        const int8v A0 = ap[La];        // tags [32La, 32La+32)
        const int8v A1 = ap[4 + La];    // tags [128+32La, ...)

        // A = bf8 e5m2 (cbsz=1), B = fp8 e4m3 (blgp=0); all scale bytes
        // wave-uniform: A 2^0; B 2^0 (hi) / 2^-4 (lo) -> lane mapping irrelevant
        f32x4 acc0 = {0.f, 0.f, 0.f, 0.f};
        f32x4 acc1 = {0.f, 0.f, 0.f, 0.f};
        acc0 = __builtin_amdgcn_mfma_scale_f32_16x16x128_f8f6f4(
                   A0, Bhi[0][0], acc0, 1, 0, 0, 127, 0, 127);
        acc1 = __builtin_amdgcn_mfma_scale_f32_16x16x128_f8f6f4(
                   A0, Bhi[1][0], acc1, 1, 0, 0, 127, 0, 127);
        acc0 = __builtin_amdgcn_mfma_scale_f32_16x16x128_f8f6f4(
                   A1, Bhi[0][1], acc0, 1, 0, 0, 127, 0, 127);
        acc1 = __builtin_amdgcn_mfma_scale_f32_16x16x128_f8f6f4(
                   A1, Bhi[1][1], acc1, 1, 0, 0, 127, 0, 127);
        acc0 = __builtin_amdgcn_mfma_scale_f32_16x16x128_f8f6f4(
                   A0, Blo[0][0], acc0, 1, 0, 0, 127, 0, 123);
        acc1 = __builtin_amdgcn_mfma_scale_f32_16x16x128_f8f6f4(
                   A0, Blo[1][0], acc1, 1, 0, 0, 127, 0, 123);
        acc0 = __builtin_amdgcn_mfma_scale_f32_16x16x128_f8f6f4(
                   A1, Blo[0][1], acc0, 1, 0, 0, 127, 0, 123);
        acc1 = __builtin_amdgcn_mfma_scale_f32_16x16x128_f8f6f4(
                   A1, Blo[1][1], acc1, 1, 0, 0, 127, 0, 123);

        // D rows replicated (A row-uniform): own tile = La&1, col lc, elem 0
        const float s = (La & 1) ? acc1[0] : acc0[0];

        const float na = LN2 * ((float)R_prev + log2f(s)) + lgC +
                         (t == end_idx ? endj : 0.f);
        if (mkC > 0) alpha = na;

        publish(alpha, nb, r);
        R_prev = r;
    }

    // ---- denominator = logsumexp over 256 alphas (lanes >= 32 are dups)
    {
        const float wm = wave_max64(alpha);
        const float ex = (l < 32) ? __expf(alpha - wm) : 0.f;
        const float sw = wave_sum64(ex);
        if (l == 0) { red[w][0] = wm; red[w][1] = sw; }
    }

    // ---- numerator (gather path score)
    float np = 0.f;
    for (int t = tid; t < Tn; t += 512) {
        const int   tg = (int)tags[b * Tn + t];
        const float e  = inputs[bTK + (size_t)t * Kn + tg];
        if (t == 0) {
            np += e + start_t[tg];
        } else {
            const float mf = (float)mask[b * Tn + t];
            const int   tq = (int)tags[b * Tn + t - 1];
            np += mf * (e + trans[tq * Kn + tg]);
        }
    }
    np = wave_sum64(np);
    if (l == 0) atomicAdd(&sh_np, np);
    __syncthreads();

    if (tid == 0) {
        float Rf = red[0][0];
#pragma unroll
        for (int q = 1; q < 8; ++q) Rf = fmaxf(Rf, red[q][0]);
        float S = 0.f;
#pragma unroll
        for (int q = 0; q < 8; ++q) S += red[q][1] * __expf(red[q][0] - Rf);
        const float denom = Rf + __logf(S);
        const float numer = sh_np + end_t[(int)tags[b * Tn + end_idx]];
        atomicAdd(out, numer - denom);
    }
}

}  // namespace

extern "C" void kernel_launch(void* const* d_in, const int* in_sizes, int n_in,
                              void* d_out, int out_size, void* d_ws, size_t ws_size,
                              hipStream_t stream) {
    const float*     inputs  = (const float*)d_in[0];
    const long long* tags    = (const long long*)d_in[1];
    const int*       mask    = (const int*)d_in[2];
    const float*     trans   = (const float*)d_in[3];
    const float*     start_t = (const float*)d_in[4];
    const float*     end_t   = (const float*)d_in[5];
    float* out = (float*)d_out;

    hipMemsetAsync(out, 0, sizeof(float), stream);
    crf_kernel<<<dim3(Bn), dim3(512), 0, stream>>>(inputs, tags, mask, trans,
                                                   start_t, end_t, out);
}